// Round 4
// baseline (1625.189 us; speedup 1.0000x reference)
//
#include <hip/hip_runtime.h>
#include <hip/hip_bf16.h>

#define BSZ 128
#define NSQ 1024
#define NSTEPC 8
#define IND 768
#define HIDD 512
#define G4D 2048
#define MLPD 512
#define NEGV -100000.0f
#define KSGATE 8  // K-split for gates gemm (1280 = 8 x 160)
#define MSPLIT 4  // m-split for scores kernel

typedef __attribute__((ext_vector_type(4))) float f32x4;
typedef __attribute__((ext_vector_type(8))) short short8v;

__device__ __forceinline__ void gl16(const unsigned short* g, unsigned short* l) {
  __builtin_amdgcn_global_load_lds(
      (const __attribute__((address_space(1))) unsigned int*)(g),
      (__attribute__((address_space(3))) unsigned int*)(l), 16, 0, 0);
}

__device__ __forceinline__ void split2(float4 f0, float4 f1, short8v& hi, short8v& lo) {
  float fv[8] = {f0.x, f0.y, f0.z, f0.w, f1.x, f1.y, f1.z, f1.w};
#pragma unroll
  for (int j = 0; j < 8; ++j) {
    const unsigned ub = __builtin_bit_cast(unsigned, fv[j]);
    const unsigned hb = ub & 0xFFFF0000u;
    const float lf = fv[j] - __builtin_bit_cast(float, hb);
    hi[j] = (short)(hb >> 16);
    lo[j] = (short)(__builtin_bit_cast(unsigned, lf) >> 16);
  }
}

// tanh(x) = 1 - 2/(e^{2x}+1)
__device__ __forceinline__ float tanh_fast(float x) {
  x = fminf(fmaxf(x, -15.0f), 15.0f);
  float e = __builtin_amdgcn_exp2f(x * 2.8853900817779268f);
  float r = __builtin_amdgcn_rcpf(e + 1.0f);
  return fmaf(-2.0f, r, 1.0f);
}

// ---------------- one-time: split W1c and [W_ih|W_hh] into bf16 hi/lo planes,
// tiled layout: unit16B = ((rb*NT + tile)*128 + row128)*4 + slot, slot = c4 ^ ((row>>1)&3)
__global__ __launch_bounds__(256) void k_prep_w(
    const float* __restrict__ W1c, const float* __restrict__ W_ih,
    const float* __restrict__ W_hh,
    unsigned short* __restrict__ wch, unsigned short* __restrict__ wcl,
    unsigned short* __restrict__ wgh, unsigned short* __restrict__ wgl) {
  int c = blockIdx.x * 256 + threadIdx.x;
  const float* src;
  unsigned short *dh, *dl;
  size_t unit;
  if (c < 49152) {  // W1c: 512 rows x 96 chunks (NT=24)
    const int row = c / 96, wc = c - row * 96;
    const int tile = wc >> 2, c4 = wc & 3;
    const int slot = c4 ^ ((row >> 1) & 3);
    unit = ((size_t)((row >> 7) * 24 + tile) * 128 + (row & 127)) * 4 + slot;
    src = W1c + (size_t)row * IND + wc * 8;
    dh = wch; dl = wcl;
  } else {
    c -= 49152;
    if (c >= 327680) return;  // Wg: 2048 rows x 160 chunks (NT=40)
    const int row = c / 160, wc = c - row * 160;
    const int k0 = wc * 8;
    const int tile = wc >> 2, c4 = wc & 3;
    const int slot = c4 ^ ((row >> 1) & 3);
    unit = ((size_t)((row >> 7) * 40 + tile) * 128 + (row & 127)) * 4 + slot;
    src = (k0 < IND) ? (W_ih + (size_t)row * IND + k0)
                     : (W_hh + (size_t)row * HIDD + (k0 - IND));
    dh = wgh; dl = wgl;
  }
  const float4 f0 = *(const float4*)src, f1 = *(const float4*)(src + 4);
  short8v hi, lo;
  split2(f0, f1, hi, lo);
  *(short8v*)(dh + unit * 8) = hi;
  *(short8v*)(dl + unit * 8) = lo;
}

// ---------------- init: mask, c=0, lp=0, cnt=0, xh planes = [split(target_emb) | 0]
__global__ __launch_bounds__(256) void k_init2(
    const float* __restrict__ te, const int* __restrict__ cl,
    float* __restrict__ mask, float* __restrict__ cst, float* __restrict__ lp,
    int* __restrict__ cnt,
    unsigned short* __restrict__ xhh, unsigned short* __restrict__ xhl) {
  const int b = blockIdx.x, tid = threadIdx.x;
  const int L = cl[b];
  for (int n = tid; n < NSQ; n += 256) mask[(size_t)b * NSQ + n] = (n >= L) ? NEGV : 0.0f;
  for (int j = tid; j < HIDD; j += 256) cst[(size_t)b * HIDD + j] = 0.0f;
  if (tid == 0) { lp[b] = 0.0f; cnt[b] = 0; }
  if (tid < 160) {  // 160 chunks per row (K=1280)
    const int tile = tid >> 2, c4 = tid & 3;
    const int slot = c4 ^ ((b >> 1) & 3);
    const size_t ub = (((size_t)tile * 128 + b) * 4 + slot) * 8;
    short8v hi = {}, lo = {};
    if (tid < 96) {
      const float* s = te + (size_t)b * IND + tid * 8;
      split2(*(const float4*)s, *(const float4*)(s + 4), hi, lo);
    }
    *(short8v*)&xhh[ub] = hi;
    *(short8v*)&xhl[ub] = lo;
  }
}

// ---------------- ctx_part GEMM (split-bf16, 3 MFMA products)
// cp[b][m][n] = sum_k ctx[b,n,k]*W1c[m,k] + b1[m]
// 512 thr / 8 waves; tile m=256 (4 m-waves), n=128 (2 n-waves), wave 64x64; BK=32.
__global__ __launch_bounds__(512) void k_ctx3(
    const float* __restrict__ ctx,
    const unsigned short* __restrict__ wch, const unsigned short* __restrict__ wcl,
    const float* __restrict__ bias, const int* __restrict__ clen,
    float* __restrict__ cp) {
  __shared__ __align__(16) unsigned short sWh[8192], sWl[8192];  // 256 rows x 32
  __shared__ __align__(16) unsigned short sCh[4096], sCl[4096];  // 128 rows x 32
  const int i0 = blockIdx.y * 128;
  const int b = blockIdx.y >> 3;
  const int nbase = i0 & 1023;
  if (nbase >= clen[b]) return;
  const int m0 = blockIdx.x * 256;
  const int rb0 = blockIdx.x * 2;
  const int tid = threadIdx.x;
  const int lane = tid & 63, wid = tid >> 6;
  const int wm = wid & 3, wn = wid >> 2;
  const int l15 = lane & 15, l4 = lane >> 4;
  const int crow = tid >> 2, cc4 = tid & 3;
  const int ckread = cc4 ^ ((crow >> 1) & 3);
  const float* csrc = ctx + (size_t)(i0 + crow) * IND + ckread * 8;

  f32x4 acc[4][4] = {};  // [fm][fn]
  for (int t = 0; t < 24; ++t) {
#pragma unroll
    for (int i = 0; i < 4; ++i) {  // stage W: 32KB, 32 segments of 1KB
      const int s = wid * 4 + i;
      const int p = s >> 4, q = s & 15;
      const int rbh = q >> 3;
      const unsigned short* g = (p ? wcl : wch) +
          ((size_t)((rb0 + rbh) * 24 + t)) * 4096 + (q & 7) * 512 + lane * 8;
      unsigned short* l = (p ? sWl : sWh) + q * 512;
      gl16(g, l);
    }
    {  // stage ctx: reg-split, linear tid*16B ds_write, pre-swizzled src
      const float* s = csrc + t * 32;
      short8v hi, lo;
      split2(*(const float4*)s, *(const float4*)(s + 4), hi, lo);
      *(short8v*)&sCh[tid * 8] = hi;
      *(short8v*)&sCl[tid * 8] = lo;
    }
    __syncthreads();
    short8v ah[4], al[4], bh[4], bl[4];
#pragma unroll
    for (int f = 0; f < 4; ++f) {
      const int rw = wm * 64 + f * 16 + l15;
      const int sw = l4 ^ ((rw >> 1) & 3);
      ah[f] = *(const short8v*)&sWh[rw * 32 + sw * 8];
      al[f] = *(const short8v*)&sWl[rw * 32 + sw * 8];
      const int rc = wn * 64 + f * 16 + l15;
      const int sc = l4 ^ ((rc >> 1) & 3);
      bh[f] = *(const short8v*)&sCh[rc * 32 + sc * 8];
      bl[f] = *(const short8v*)&sCl[rc * 32 + sc * 8];
    }
#pragma unroll
    for (int fm = 0; fm < 4; ++fm)
#pragma unroll
      for (int fn = 0; fn < 4; ++fn) {
        acc[fm][fn] = __builtin_amdgcn_mfma_f32_16x16x32_bf16(ah[fm], bh[fn], acc[fm][fn], 0, 0, 0);
        acc[fm][fn] = __builtin_amdgcn_mfma_f32_16x16x32_bf16(ah[fm], bl[fn], acc[fm][fn], 0, 0, 0);
        acc[fm][fn] = __builtin_amdgcn_mfma_f32_16x16x32_bf16(al[fm], bh[fn], acc[fm][fn], 0, 0, 0);
      }
    __syncthreads();
  }
#pragma unroll
  for (int fm = 0; fm < 4; ++fm) {
#pragma unroll
    for (int r = 0; r < 4; ++r) {
      const int m = m0 + wm * 64 + fm * 16 + l4 * 4 + r;
      const float bb = bias[m];
      float* dst = cp + (((size_t)(b * MLPD + m)) << 10) + nbase + wn * 64 + l15;
#pragma unroll
      for (int fn = 0; fn < 4; ++fn)
        dst[fn * 16] = acc[fm][fn][r] + bb;
    }
  }
}

// ---------------- gates GEMM: gp[ks][i][n] partial over K-chunk ks (160 wide)
__global__ __launch_bounds__(256) void k_gates(
    const unsigned short* __restrict__ xhh, const unsigned short* __restrict__ xhl,
    const unsigned short* __restrict__ wgh, const unsigned short* __restrict__ wgl,
    float* __restrict__ gp) {
  __shared__ __align__(16) unsigned short sAh[4096], sAl[4096], sBh[4096], sBl[4096];
  const int nb = blockIdx.x;  // n-block (16)
  const int ks = blockIdx.y;  // K-chunk (8)
  const int tid = threadIdx.x;
  const int lane = tid & 63, wid = tid >> 6;
  const int wm = wid >> 1, wn = wid & 1;
  const int l15 = lane & 15, l4 = lane >> 4;
  f32x4 acc[4][4] = {};  // [fi][fn]
  for (int t = 0; t < 5; ++t) {
    const int gt = ks * 5 + t;
#pragma unroll
    for (int i = 0; i < 8; ++i) {
      const int v = wid * 1024 + i * 4096;
      const int mm = v >> 13;  // 0..3: Ah, Al, Bh, Bl
      const int offs = (v & 8191) >> 1;
      const unsigned short* g;
      unsigned short* l;
      if (mm == 0)      { g = xhh + (size_t)gt * 4096 + offs; l = sAh + offs; }
      else if (mm == 1) { g = xhl + (size_t)gt * 4096 + offs; l = sAl + offs; }
      else if (mm == 2) { g = wgh + ((size_t)nb * 40 + gt) * 4096 + offs; l = sBh + offs; }
      else              { g = wgl + ((size_t)nb * 40 + gt) * 4096 + offs; l = sBl + offs; }
      gl16(g + lane * 8, l);
    }
    __syncthreads();
    short8v ahv[4], alv[4], bhv[4], blv[4];
#pragma unroll
    for (int f = 0; f < 4; ++f) {
      const int ri = wm * 64 + f * 16 + l15;
      const int sa = l4 ^ ((ri >> 1) & 3);
      ahv[f] = *(const short8v*)&sAh[ri * 32 + sa * 8];
      alv[f] = *(const short8v*)&sAl[ri * 32 + sa * 8];
      const int rn = wn * 64 + f * 16 + l15;
      const int sb = l4 ^ ((rn >> 1) & 3);
      bhv[f] = *(const short8v*)&sBh[rn * 32 + sb * 8];
      blv[f] = *(const short8v*)&sBl[rn * 32 + sb * 8];
    }
#pragma unroll
    for (int fi = 0; fi < 4; ++fi)
#pragma unroll
      for (int fn = 0; fn < 4; ++fn) {
        acc[fi][fn] = __builtin_amdgcn_mfma_f32_16x16x32_bf16(ahv[fi], bhv[fn], acc[fi][fn], 0, 0, 0);
        acc[fi][fn] = __builtin_amdgcn_mfma_f32_16x16x32_bf16(ahv[fi], blv[fn], acc[fi][fn], 0, 0, 0);
        acc[fi][fn] = __builtin_amdgcn_mfma_f32_16x16x32_bf16(alv[fi], bhv[fn], acc[fi][fn], 0, 0, 0);
      }
    __syncthreads();
  }
#pragma unroll
  for (int fi = 0; fi < 4; ++fi) {
#pragma unroll
    for (int r = 0; r < 4; ++r) {
      const int i = wm * 64 + fi * 16 + l4 * 4 + r;
      float* dst = gp + ((size_t)ks * BSZ + i) * G4D + nb * 128 + wn * 64 + l15;
#pragma unroll
      for (int fn = 0; fn < 4; ++fn)
        dst[fn * 16] = acc[fi][fn][r];
    }
  }
}

// ---------------- gate reduce + LSTM activations + h-plane write + fused hproj
__global__ __launch_bounds__(512) void k_lstm2(
    const float* __restrict__ gp, const float* __restrict__ b_ih,
    const float* __restrict__ b_hh, const float* __restrict__ W1h,
    float* __restrict__ cst,
    unsigned short* __restrict__ xhh, unsigned short* __restrict__ xhl,
    float* __restrict__ hpp) {
  __shared__ float hs[HIDD];
  const int b = blockIdx.x, j = threadIdx.x;
  float g[4];
#pragma unroll
  for (int q = 0; q < 4; ++q) {
    float s = b_ih[q * HIDD + j] + b_hh[q * HIDD + j];
#pragma unroll
    for (int ks = 0; ks < KSGATE; ++ks)
      s += gp[((size_t)ks * BSZ + b) * G4D + q * HIDD + j];
    g[q] = s;
  }
  const float c_old = cst[(size_t)b * HIDD + j];
  const float ig = 1.0f / (1.0f + expf(-g[0]));
  const float fg = 1.0f / (1.0f + expf(-g[1]));
  const float gg = tanhf(g[2]);
  const float og = 1.0f / (1.0f + expf(-g[3]));
  const float cn = fg * c_old + ig * gg;
  const float hn = og * tanhf(cn);
  cst[(size_t)b * HIDD + j] = cn;
  hs[j] = hn;
  {  // write h into xh planes at k = 768 + j
    const int tile = 24 + (j >> 5);
    const int c4 = (j >> 3) & 3;
    const int slot = c4 ^ ((b >> 1) & 3);
    const size_t u16i = (((size_t)tile * 128 + b) * 4 + slot) * 8 + (j & 7);
    const unsigned ubh = __builtin_bit_cast(unsigned, hn) & 0xFFFF0000u;
    const float lf = hn - __builtin_bit_cast(float, ubh);
    xhh[u16i] = (unsigned short)(ubh >> 16);
    xhl[u16i] = (unsigned short)(__builtin_bit_cast(unsigned, lf) >> 16);
  }
  __syncthreads();
  // fused hproj: hp[b][m] = sum_k h[k] * W1h[m][k], m = j
  const float* wr = W1h + (size_t)j * HIDD;
  float s = 0.0f;
#pragma unroll 4
  for (int k = 0; k < HIDD; k += 4) {
    const float4 h4 = *(const float4*)&hs[k];
    const float4 w4 = *(const float4*)&wr[k];
    s = fmaf(h4.x, w4.x, fmaf(h4.y, w4.y, fmaf(h4.z, w4.z, fmaf(h4.w, w4.w, s))));
  }
  hpp[(size_t)b * HIDD + j] = s;
}

// ---------------- fused scores + (last block per row) argmax/LSE/feedback
__global__ __launch_bounds__(256) void k_scoremax(
    const float* __restrict__ cp, const float* __restrict__ hpp,
    const float* __restrict__ w2, const int* __restrict__ clen,
    float* __restrict__ psc, int* __restrict__ cnt,
    float* __restrict__ mask, const float* __restrict__ gum,
    const float* __restrict__ b2p, float* __restrict__ lp,
    const float* __restrict__ ctx,
    unsigned short* __restrict__ xhh, unsigned short* __restrict__ xhl,
    float* __restrict__ outv, int step) {
  const int mh = blockIdx.x;  // [0,MSPLIT)
  const int b = blockIdx.y;
  const int tid = threadIdx.x;
  __shared__ float hsm[128], wsm[128];
  __shared__ float rv[256], rs[256], rm[256];
  __shared__ int ri[256];
  __shared__ int lastFlag, sel;
  const int len = clen[b];
  if (tid < 128) {
    hsm[tid] = hpp[(size_t)b * MLPD + mh * 128 + tid];
    wsm[tid] = w2[mh * 128 + tid];
  }
  __syncthreads();
  const int n0 = tid * 4;
  if (n0 < len) {
    float ax = 0, ay = 0, az = 0, aw = 0;
    const float* base = cp + ((size_t)b * MLPD + mh * 128) * NSQ + n0;
#pragma unroll 4
    for (int mm = 0; mm < 128; ++mm) {
      const float4 c4 = *(const float4*)(base + (size_t)mm * NSQ);
      const float h = hsm[mm], w = wsm[mm];
      ax = fmaf(tanh_fast(c4.x + h), w, ax);
      ay = fmaf(tanh_fast(c4.y + h), w, ay);
      az = fmaf(tanh_fast(c4.z + h), w, az);
      aw = fmaf(tanh_fast(c4.w + h), w, aw);
    }
    *(float4*)(psc + ((size_t)b * MSPLIT + mh) * NSQ + n0) = make_float4(ax, ay, az, aw);
  }
  __threadfence();   // release psc slice (device scope)
  __syncthreads();
  if (tid == 0) {
    const int old = atomicAdd(&cnt[b], 1);
    lastFlag = (old == MSPLIT - 1);
  }
  __syncthreads();
  if (!lastFlag) return;
  __threadfence();   // acquire: all 4 psc slices for row b visible

  // ---- phase B: argmax + LSE + lp + mask update + x-plane feedback
  const float b2 = b2p[0];
  const float4 m4 = *(const float4*)(mask + (size_t)b * NSQ + n0);
  float sc[4] = {b2 + m4.x, b2 + m4.y, b2 + m4.z, b2 + m4.w};
#pragma unroll
  for (int q = 0; q < MSPLIT; ++q) {
    const float4 p4 = *(const float4*)(psc + ((size_t)b * MSPLIT + q) * NSQ + n0);
    sc[0] += p4.x; sc[1] += p4.y; sc[2] += p4.z; sc[3] += p4.w;
  }
  const float4 g4 = *(const float4*)(gum + ((size_t)step * BSZ + b) * NSQ + n0);
  const float gv[4] = {g4.x, g4.y, g4.z, g4.w};
  float bestv = -1e30f, bests = 0.0f, msc = -1e30f;
  int bestn = 0;
#pragma unroll
  for (int q = 0; q < 4; ++q) {
    const float v = sc[q] + gv[q];
    if (v > bestv) { bestv = v; bestn = n0 + q; bests = sc[q]; }
    msc = fmaxf(msc, sc[q]);
  }
  rv[tid] = bestv; ri[tid] = bestn; rs[tid] = bests; rm[tid] = msc;
  __syncthreads();
  for (int o = 128; o > 0; o >>= 1) {
    if (tid < o) {
      if (rv[tid + o] > rv[tid] || (rv[tid + o] == rv[tid] && ri[tid + o] < ri[tid])) {
        rv[tid] = rv[tid + o]; ri[tid] = ri[tid + o]; rs[tid] = rs[tid + o];
      }
      rm[tid] = fmaxf(rm[tid], rm[tid + o]);
    }
    __syncthreads();
  }
  const float M = rm[0];
  __syncthreads();
  float se = 0.0f;
#pragma unroll
  for (int q = 0; q < 4; ++q)
    se += __builtin_amdgcn_exp2f((sc[q] - M) * 1.4426950408889634f);
  rm[tid] = se;
  __syncthreads();
  for (int o = 128; o > 0; o >>= 1) {
    if (tid < o) rm[tid] += rm[tid + o];
    __syncthreads();
  }
  if (tid == 0) {
    const int n = ri[0];
    const float lse = M + logf(rm[0]);
    const float nlp = lp[b] + rs[0] - lse;
    lp[b] = nlp;
    mask[(size_t)b * NSQ + n] = NEGV;
    outv[step * BSZ + b] = (float)n;
    if (step == NSTEPC - 1) outv[NSTEPC * BSZ + b] = nlp;
    sel = n;
    cnt[b] = 0;  // reset for next step (all increments for b are done)
  }
  __syncthreads();
  const int n = sel;
  if (tid < 96) {  // x feedback: split ctx row into xh planes (96 chunks)
    const float* src = ctx + ((size_t)b * NSQ + n) * IND + tid * 8;
    const int tile = tid >> 2, c4 = tid & 3;
    const int slot = c4 ^ ((b >> 1) & 3);
    const size_t ub = (((size_t)tile * 128 + b) * 4 + slot) * 8;
    short8v hi, lo;
    split2(*(const float4*)src, *(const float4*)(src + 4), hi, lo);
    *(short8v*)&xhh[ub] = hi;
    *(short8v*)&xhl[ub] = lo;
  }
}

extern "C" void kernel_launch(void* const* d_in, const int* in_sizes, int n_in,
                              void* d_out, int out_size, void* d_ws, size_t ws_size,
                              hipStream_t stream) {
  const float* target_emb = (const float*)d_in[0];
  const float* ctx_emb   = (const float*)d_in[1];
  const int*   ctx_len   = (const int*)d_in[3];
  const float* W_ih = (const float*)d_in[5];
  const float* W_hh = (const float*)d_in[6];
  const float* b_ih = (const float*)d_in[7];
  const float* b_hh = (const float*)d_in[8];
  const float* W1c  = (const float*)d_in[9];
  const float* W1h  = (const float*)d_in[10];
  const float* b1   = (const float*)d_in[11];
  const float* w2   = (const float*)d_in[12];
  const float* b2   = (const float*)d_in[13];
  const float* gumbel = (const float*)d_in[14];
  float* out = (float*)d_out;

  float* ws = (float*)d_ws;
  size_t off = 0;
  auto alloc = [&](size_t n) { float* p = ws + off; off += (n + 63) & ~(size_t)63; return p; };

  float* cp   = alloc((size_t)BSZ * MLPD * NSQ);        // 268 MB
  float* gp   = alloc((size_t)KSGATE * BSZ * G4D);
  float* hpp  = alloc((size_t)BSZ * MLPD);
  float* psc  = alloc((size_t)BSZ * MSPLIT * NSQ);
  float* mask = alloc((size_t)BSZ * NSQ);
  float* cst  = alloc((size_t)BSZ * HIDD);
  float* lp   = alloc(128);
  int*   cnt  = (int*)alloc(128);
  unsigned short* wch = (unsigned short*)alloc(196608);   // 512x768 u16
  unsigned short* wcl = (unsigned short*)alloc(196608);
  unsigned short* wgh = (unsigned short*)alloc(1310720);  // 2048x1280 u16
  unsigned short* wgl = (unsigned short*)alloc(1310720);
  unsigned short* xhh = (unsigned short*)alloc(81920);    // 128x1280 u16
  unsigned short* xhl = (unsigned short*)alloc(81920);

  k_prep_w<<<1472, 256, 0, stream>>>(W1c, W_ih, W_hh, wch, wcl, wgh, wgl);
  k_init2<<<BSZ, 256, 0, stream>>>(target_emb, ctx_len, mask, cst, lp, cnt, xhh, xhl);
  k_ctx3<<<dim3(2, 1024), 512, 0, stream>>>(ctx_emb, wch, wcl, b1, ctx_len, cp);

  for (int t = 0; t < NSTEPC; ++t) {
    k_gates<<<dim3(16, KSGATE), 256, 0, stream>>>(xhh, xhl, wgh, wgl, gp);
    k_lstm2<<<BSZ, 512, 0, stream>>>(gp, b_ih, b_hh, W1h, cst, xhh, xhl, hpp);
    k_scoremax<<<dim3(MSPLIT, BSZ), 256, 0, stream>>>(
        cp, hpp, w2, ctx_len, psc, cnt, mask, gumbel, b2, lp,
        ctx_emb, xhh, xhl, out, t);
  }
}

// Round 5
// 1056.283 us; speedup vs baseline: 1.5386x; 1.5386x over previous
//
#include <hip/hip_runtime.h>
#include <hip/hip_bf16.h>

#define BSZ 128
#define NSQ 1024
#define NSTEPC 8
#define IND 768
#define HIDD 512
#define G4D 2048
#define MLPD 512
#define NEGV -100000.0f
#define KSGATE 8  // K-split for gates gemm (1280 = 8 x 160)
#define MSPLIT 4  // m-split for scores kernel

typedef __attribute__((ext_vector_type(4))) float f32x4;
typedef __attribute__((ext_vector_type(8))) short short8v;

__device__ __forceinline__ void gl16(const unsigned short* g, unsigned short* l) {
  __builtin_amdgcn_global_load_lds(
      (const __attribute__((address_space(1))) unsigned int*)(g),
      (__attribute__((address_space(3))) unsigned int*)(l), 16, 0, 0);
}

__device__ __forceinline__ void split2(float4 f0, float4 f1, short8v& hi, short8v& lo) {
  float fv[8] = {f0.x, f0.y, f0.z, f0.w, f1.x, f1.y, f1.z, f1.w};
#pragma unroll
  for (int j = 0; j < 8; ++j) {
    const unsigned ub = __builtin_bit_cast(unsigned, fv[j]);
    const unsigned hb = ub & 0xFFFF0000u;
    const float lf = fv[j] - __builtin_bit_cast(float, hb);
    hi[j] = (short)(hb >> 16);
    lo[j] = (short)(__builtin_bit_cast(unsigned, lf) >> 16);
  }
}

// tanh(x) = 1 - 2/(e^{2x}+1)
__device__ __forceinline__ float tanh_fast(float x) {
  x = fminf(fmaxf(x, -15.0f), 15.0f);
  float e = __builtin_amdgcn_exp2f(x * 2.8853900817779268f);
  float r = __builtin_amdgcn_rcpf(e + 1.0f);
  return fmaf(-2.0f, r, 1.0f);
}

// ---------------- one-time: split W1c and [W_ih|W_hh] into bf16 hi/lo planes,
// tiled layout: unit16B = ((rb*NT + tile)*128 + row128)*4 + slot, slot = c4 ^ ((row>>1)&3)
__global__ __launch_bounds__(256) void k_prep_w(
    const float* __restrict__ W1c, const float* __restrict__ W_ih,
    const float* __restrict__ W_hh,
    unsigned short* __restrict__ wch, unsigned short* __restrict__ wcl,
    unsigned short* __restrict__ wgh, unsigned short* __restrict__ wgl) {
  int c = blockIdx.x * 256 + threadIdx.x;
  const float* src;
  unsigned short *dh, *dl;
  size_t unit;
  if (c < 49152) {  // W1c: 512 rows x 96 chunks (NT=24)
    const int row = c / 96, wc = c - row * 96;
    const int tile = wc >> 2, c4 = wc & 3;
    const int slot = c4 ^ ((row >> 1) & 3);
    unit = ((size_t)((row >> 7) * 24 + tile) * 128 + (row & 127)) * 4 + slot;
    src = W1c + (size_t)row * IND + wc * 8;
    dh = wch; dl = wcl;
  } else {
    c -= 49152;
    if (c >= 327680) return;  // Wg: 2048 rows x 160 chunks (NT=40)
    const int row = c / 160, wc = c - row * 160;
    const int k0 = wc * 8;
    const int tile = wc >> 2, c4 = wc & 3;
    const int slot = c4 ^ ((row >> 1) & 3);
    unit = ((size_t)((row >> 7) * 40 + tile) * 128 + (row & 127)) * 4 + slot;
    src = (k0 < IND) ? (W_ih + (size_t)row * IND + k0)
                     : (W_hh + (size_t)row * HIDD + (k0 - IND));
    dh = wgh; dl = wgl;
  }
  const float4 f0 = *(const float4*)src, f1 = *(const float4*)(src + 4);
  short8v hi, lo;
  split2(f0, f1, hi, lo);
  *(short8v*)(dh + unit * 8) = hi;
  *(short8v*)(dl + unit * 8) = lo;
}

// ---------------- one-time: split ctx_emb into tiled hi/lo planes (active row-blocks only)
__global__ __launch_bounds__(256) void k_prep_ctx(
    const float* __restrict__ ctx, const int* __restrict__ clen,
    unsigned short* __restrict__ cxh, unsigned short* __restrict__ cxl) {
  const int rb = blockIdx.x;            // 1024 blocks of 128 rows
  const int b = rb >> 3;
  const int nbase = (rb & 7) << 7;
  if (nbase >= clen[b]) return;
  const int tid = threadIdx.x;
  const float* src = ctx + (size_t)rb * 128 * IND;
  for (int it = 0; it < 48; ++it) {
    const int cc = it * 256 + tid;                 // 12288 = 128 rows x 96 chunks
    const int row = (int)(((unsigned)cc * 21846u) >> 21);  // cc/96
    const int wc = cc - row * 96;
    const int t = wc >> 2, c4 = wc & 3;
    const int slot = c4 ^ ((row >> 1) & 3);
    const size_t u = (((size_t)(rb * 24 + t)) * 128 + row) * 4 + slot;
    const float* s = src + (size_t)row * IND + wc * 8;
    short8v hi, lo;
    split2(*(const float4*)s, *(const float4*)(s + 4), hi, lo);
    *(short8v*)(cxh + u * 8) = hi;
    *(short8v*)(cxl + u * 8) = lo;
  }
}

// ---------------- init: mask, c=0, lp=0, xh planes = [split(target_emb) | 0]
__global__ __launch_bounds__(256) void k_init2(
    const float* __restrict__ te, const int* __restrict__ cl,
    float* __restrict__ mask, float* __restrict__ cst, float* __restrict__ lp,
    unsigned short* __restrict__ xhh, unsigned short* __restrict__ xhl) {
  const int b = blockIdx.x, tid = threadIdx.x;
  const int L = cl[b];
  for (int n = tid; n < NSQ; n += 256) mask[(size_t)b * NSQ + n] = (n >= L) ? NEGV : 0.0f;
  for (int j = tid; j < HIDD; j += 256) cst[(size_t)b * HIDD + j] = 0.0f;
  if (tid == 0) lp[b] = 0.0f;
  if (tid < 160) {  // 160 chunks per row (K=1280)
    const int tile = tid >> 2, c4 = tid & 3;
    const int slot = c4 ^ ((b >> 1) & 3);
    const size_t ub = (((size_t)tile * 128 + b) * 4 + slot) * 8;
    short8v hi = {}, lo = {};
    if (tid < 96) {
      const float* s = te + (size_t)b * IND + tid * 8;
      split2(*(const float4*)s, *(const float4*)(s + 4), hi, lo);
    }
    *(short8v*)&xhh[ub] = hi;
    *(short8v*)&xhl[ub] = lo;
  }
}

// ---------------- ctx_part GEMM, all-plane gl16 staging (m97-style):
// cp[b][m][n] = sum_k ctx[b,n,k]*W1c[m,k] + b1[m]; 3 MFMA products (hh+hl+lh)
// 256 thr / 4 waves; tile m=128 x n=128, wave 64x64; BK=32, 24 K-steps.
__global__ __launch_bounds__(256) void k_ctx4(
    const unsigned short* __restrict__ cxh, const unsigned short* __restrict__ cxl,
    const unsigned short* __restrict__ wch, const unsigned short* __restrict__ wcl,
    const float* __restrict__ bias, const int* __restrict__ clen,
    float* __restrict__ cp) {
  __shared__ __align__(16) unsigned short sWh[4096], sWl[4096], sCh[4096], sCl[4096];
  const int rbC = blockIdx.y;
  const int b = rbC >> 3;
  const int nbase = (rbC & 7) << 7;
  if (nbase >= clen[b]) return;
  const int rbW = blockIdx.x;
  const int m0 = rbW << 7;
  const int tid = threadIdx.x;
  const int lane = tid & 63, wid = tid >> 6;
  const int wm = wid & 1, wn = wid >> 1;
  const int l15 = lane & 15, l4 = lane >> 4;
  // wave w stages plane w (8KB = 8 segments of 1KB)
  unsigned short* sP = (wid == 0) ? sWh : (wid == 1) ? sWl : (wid == 2) ? sCh : sCl;
  const unsigned short* gP = (wid == 0) ? wch : (wid == 1) ? wcl : (wid == 2) ? cxh : cxl;
  const size_t gBase = ((size_t)((wid < 2) ? rbW : rbC) * 24) * 4096 + lane * 8;

  f32x4 acc[4][4] = {};  // [fm][fn]
  for (int t = 0; t < 24; ++t) {
#pragma unroll
    for (int q = 0; q < 8; ++q)
      gl16(gP + gBase + t * 4096 + q * 512, sP + q * 512);
    __syncthreads();
    short8v ah[4], al[4], bh[4], bl[4];
#pragma unroll
    for (int f = 0; f < 4; ++f) {
      const int rw = wm * 64 + f * 16 + l15;
      const int so = (l4 ^ ((rw >> 1) & 3)) << 3;
      ah[f] = *(const short8v*)&sWh[rw * 32 + so];
      al[f] = *(const short8v*)&sWl[rw * 32 + so];
      const int rc = wn * 64 + f * 16 + l15;
      const int sc = (l4 ^ ((rc >> 1) & 3)) << 3;
      bh[f] = *(const short8v*)&sCh[rc * 32 + sc];
      bl[f] = *(const short8v*)&sCl[rc * 32 + sc];
    }
#pragma unroll
    for (int fm = 0; fm < 4; ++fm)
#pragma unroll
      for (int fn = 0; fn < 4; ++fn) {
        acc[fm][fn] = __builtin_amdgcn_mfma_f32_16x16x32_bf16(ah[fm], bh[fn], acc[fm][fn], 0, 0, 0);
        acc[fm][fn] = __builtin_amdgcn_mfma_f32_16x16x32_bf16(ah[fm], bl[fn], acc[fm][fn], 0, 0, 0);
        acc[fm][fn] = __builtin_amdgcn_mfma_f32_16x16x32_bf16(al[fm], bh[fn], acc[fm][fn], 0, 0, 0);
      }
    __syncthreads();
  }
#pragma unroll
  for (int fm = 0; fm < 4; ++fm) {
#pragma unroll
    for (int r = 0; r < 4; ++r) {
      const int m = m0 + wm * 64 + fm * 16 + l4 * 4 + r;
      const float bb = bias[m];
      float* dst = cp + (((size_t)(b * MLPD + m)) << 10) + nbase + wn * 64 + l15;
#pragma unroll
      for (int fn = 0; fn < 4; ++fn)
        dst[fn * 16] = acc[fm][fn][r] + bb;
    }
  }
}

// ---------------- FALLBACK ctx GEMM (R2): in-kernel ctx split, m=256/n=64
__global__ __launch_bounds__(256) void k_ctx2(
    const float* __restrict__ ctx,
    const unsigned short* __restrict__ wch, const unsigned short* __restrict__ wcl,
    const float* __restrict__ bias, const int* __restrict__ clen,
    float* __restrict__ cp) {
  __shared__ __align__(16) unsigned short sWh[8192], sWl[8192];
  __shared__ __align__(16) unsigned short sCh[2048], sCl[2048];
  const int i0 = blockIdx.y * 64;
  const int b = i0 >> 10;
  const int nbase = i0 & 1023;
  if (nbase >= clen[b]) return;
  const int m0 = blockIdx.x * 256;
  const int rb0 = blockIdx.x * 2;
  const int tid = threadIdx.x;
  const int lane = tid & 63, wid = tid >> 6;
  const int l15 = lane & 15, l4 = lane >> 4;
  const int crow = tid >> 2, cc4 = tid & 3;
  const int ckread = cc4 ^ ((crow >> 1) & 3);
  const float* csrc = ctx + (size_t)(i0 + crow) * IND + ckread * 8;
  f32x4 acc[4][4] = {};
  for (int t = 0; t < 24; ++t) {
#pragma unroll
    for (int i = 0; i < 8; ++i) {
      const int v = wid * 1024 + i * 4096;
      const int plane = v >> 14;
      const int rem = v & 16383;
      const int rbh = rem >> 13;
      const int offs = (rem & 8191) >> 1;
      const unsigned short* g = (plane ? wcl : wch) +
          ((size_t)((rb0 + rbh) * 24 + t)) * 4096 + offs + lane * 8;
      unsigned short* l = (plane ? sWl : sWh) + rbh * 4096 + offs;
      gl16(g, l);
    }
    {
      const float* s = csrc + t * 32;
      short8v hi, lo;
      split2(*(const float4*)s, *(const float4*)(s + 4), hi, lo);
      *(short8v*)&sCh[tid * 8] = hi;
      *(short8v*)&sCl[tid * 8] = lo;
    }
    __syncthreads();
    short8v ah[4], al[4], bh[4], bl[4];
#pragma unroll
    for (int f = 0; f < 4; ++f) {
      const int rw = wid * 64 + f * 16 + l15;
      const int sw = l4 ^ ((rw >> 1) & 3);
      ah[f] = *(const short8v*)&sWh[rw * 32 + sw * 8];
      al[f] = *(const short8v*)&sWl[rw * 32 + sw * 8];
      const int rc = f * 16 + l15;
      const int sc = l4 ^ ((rc >> 1) & 3);
      bh[f] = *(const short8v*)&sCh[rc * 32 + sc * 8];
      bl[f] = *(const short8v*)&sCl[rc * 32 + sc * 8];
    }
#pragma unroll
    for (int fm = 0; fm < 4; ++fm)
#pragma unroll
      for (int fn = 0; fn < 4; ++fn) {
        acc[fm][fn] = __builtin_amdgcn_mfma_f32_16x16x32_bf16(ah[fm], bh[fn], acc[fm][fn], 0, 0, 0);
        acc[fm][fn] = __builtin_amdgcn_mfma_f32_16x16x32_bf16(ah[fm], bl[fn], acc[fm][fn], 0, 0, 0);
        acc[fm][fn] = __builtin_amdgcn_mfma_f32_16x16x32_bf16(al[fm], bh[fn], acc[fm][fn], 0, 0, 0);
      }
    __syncthreads();
  }
#pragma unroll
  for (int fm = 0; fm < 4; ++fm) {
#pragma unroll
    for (int r = 0; r < 4; ++r) {
      const int m = m0 + wid * 64 + fm * 16 + l4 * 4 + r;
      const float bb = bias[m];
      float* dst = cp + (((size_t)(b * MLPD + m)) << 10) + nbase + l15;
#pragma unroll
      for (int fn = 0; fn < 4; ++fn)
        dst[fn * 16] = acc[fm][fn][r] + bb;
    }
  }
}

// ---------------- gates GEMM: gp[ks][i][n] partial over K-chunk ks (160 wide)
__global__ __launch_bounds__(256) void k_gates(
    const unsigned short* __restrict__ xhh, const unsigned short* __restrict__ xhl,
    const unsigned short* __restrict__ wgh, const unsigned short* __restrict__ wgl,
    float* __restrict__ gp) {
  __shared__ __align__(16) unsigned short sAh[4096], sAl[4096], sBh[4096], sBl[4096];
  const int nb = blockIdx.x;  // n-block (16)
  const int ks = blockIdx.y;  // K-chunk (8)
  const int tid = threadIdx.x;
  const int lane = tid & 63, wid = tid >> 6;
  const int wm = wid >> 1, wn = wid & 1;
  const int l15 = lane & 15, l4 = lane >> 4;
  f32x4 acc[4][4] = {};
  for (int t = 0; t < 5; ++t) {
    const int gt = ks * 5 + t;
#pragma unroll
    for (int i = 0; i < 8; ++i) {
      const int v = wid * 1024 + i * 4096;
      const int mm = v >> 13;
      const int offs = (v & 8191) >> 1;
      const unsigned short* g;
      unsigned short* l;
      if (mm == 0)      { g = xhh + (size_t)gt * 4096 + offs; l = sAh + offs; }
      else if (mm == 1) { g = xhl + (size_t)gt * 4096 + offs; l = sAl + offs; }
      else if (mm == 2) { g = wgh + ((size_t)nb * 40 + gt) * 4096 + offs; l = sBh + offs; }
      else              { g = wgl + ((size_t)nb * 40 + gt) * 4096 + offs; l = sBl + offs; }
      gl16(g + lane * 8, l);
    }
    __syncthreads();
    short8v ahv[4], alv[4], bhv[4], blv[4];
#pragma unroll
    for (int f = 0; f < 4; ++f) {
      const int ri = wm * 64 + f * 16 + l15;
      const int sa = l4 ^ ((ri >> 1) & 3);
      ahv[f] = *(const short8v*)&sAh[ri * 32 + sa * 8];
      alv[f] = *(const short8v*)&sAl[ri * 32 + sa * 8];
      const int rn = wn * 64 + f * 16 + l15;
      const int sb = l4 ^ ((rn >> 1) & 3);
      bhv[f] = *(const short8v*)&sBh[rn * 32 + sb * 8];
      blv[f] = *(const short8v*)&sBl[rn * 32 + sb * 8];
    }
#pragma unroll
    for (int fi = 0; fi < 4; ++fi)
#pragma unroll
      for (int fn = 0; fn < 4; ++fn) {
        acc[fi][fn] = __builtin_amdgcn_mfma_f32_16x16x32_bf16(ahv[fi], bhv[fn], acc[fi][fn], 0, 0, 0);
        acc[fi][fn] = __builtin_amdgcn_mfma_f32_16x16x32_bf16(ahv[fi], blv[fn], acc[fi][fn], 0, 0, 0);
        acc[fi][fn] = __builtin_amdgcn_mfma_f32_16x16x32_bf16(alv[fi], bhv[fn], acc[fi][fn], 0, 0, 0);
      }
    __syncthreads();
  }
#pragma unroll
  for (int fi = 0; fi < 4; ++fi) {
#pragma unroll
    for (int r = 0; r < 4; ++r) {
      const int i = wm * 64 + fi * 16 + l4 * 4 + r;
      float* dst = gp + ((size_t)ks * BSZ + i) * G4D + nb * 128 + wn * 64 + l15;
#pragma unroll
      for (int fn = 0; fn < 4; ++fn)
        dst[fn * 16] = acc[fi][fn][r];
    }
  }
}

// ---------------- gate reduce + LSTM activations + h-plane write + fused hproj
__global__ __launch_bounds__(512) void k_lstm2(
    const float* __restrict__ gp, const float* __restrict__ b_ih,
    const float* __restrict__ b_hh, const float* __restrict__ W1h,
    float* __restrict__ cst,
    unsigned short* __restrict__ xhh, unsigned short* __restrict__ xhl,
    float* __restrict__ hpp) {
  __shared__ float hs[HIDD];
  const int b = blockIdx.x, j = threadIdx.x;
  float g[4];
#pragma unroll
  for (int q = 0; q < 4; ++q) {
    float s = b_ih[q * HIDD + j] + b_hh[q * HIDD + j];
#pragma unroll
    for (int ks = 0; ks < KSGATE; ++ks)
      s += gp[((size_t)ks * BSZ + b) * G4D + q * HIDD + j];
    g[q] = s;
  }
  const float c_old = cst[(size_t)b * HIDD + j];
  const float ig = 1.0f / (1.0f + expf(-g[0]));
  const float fg = 1.0f / (1.0f + expf(-g[1]));
  const float gg = tanhf(g[2]);
  const float og = 1.0f / (1.0f + expf(-g[3]));
  const float cn = fg * c_old + ig * gg;
  const float hn = og * tanhf(cn);
  cst[(size_t)b * HIDD + j] = cn;
  hs[j] = hn;
  {  // write h into xh planes at k = 768 + j
    const int tile = 24 + (j >> 5);
    const int c4 = (j >> 3) & 3;
    const int slot = c4 ^ ((b >> 1) & 3);
    const size_t u16i = (((size_t)tile * 128 + b) * 4 + slot) * 8 + (j & 7);
    const unsigned ubh = __builtin_bit_cast(unsigned, hn) & 0xFFFF0000u;
    const float lf = hn - __builtin_bit_cast(float, ubh);
    xhh[u16i] = (unsigned short)(ubh >> 16);
    xhl[u16i] = (unsigned short)(__builtin_bit_cast(unsigned, lf) >> 16);
  }
  __syncthreads();
  // fused hproj: hp[b][m] = sum_k h[k] * W1h[m][k], m = j
  const float* wr = W1h + (size_t)j * HIDD;
  float s = 0.0f;
#pragma unroll 4
  for (int k = 0; k < HIDD; k += 4) {
    const float4 h4 = *(const float4*)&hs[k];
    const float4 w4 = *(const float4*)&wr[k];
    s = fmaf(h4.x, w4.x, fmaf(h4.y, w4.y, fmaf(h4.z, w4.z, fmaf(h4.w, w4.w, s))));
  }
  hpp[(size_t)b * HIDD + j] = s;
}

// ---------------- scores partial: psc[b][mh][n] = sum_m tanh(cp+hp)*w2
__global__ __launch_bounds__(256) void k_scores(
    const float* __restrict__ cp, const float* __restrict__ hpp,
    const float* __restrict__ w2, const int* __restrict__ clen,
    float* __restrict__ psc) {
  const int mh = blockIdx.x;
  const int b = blockIdx.y;
  const int tid = threadIdx.x;
  __shared__ float hsm[128], wsm[128];
  if (tid < 128) {
    hsm[tid] = hpp[(size_t)b * MLPD + mh * 128 + tid];
    wsm[tid] = w2[mh * 128 + tid];
  }
  __syncthreads();
  const int len = clen[b];
  const int n0 = tid * 4;
  if (n0 >= len) return;
  float ax = 0, ay = 0, az = 0, aw = 0;
  const float* base = cp + ((size_t)b * MLPD + mh * 128) * NSQ + n0;
#pragma unroll 4
  for (int mm = 0; mm < 128; ++mm) {
    const float4 c4 = *(const float4*)(base + (size_t)mm * NSQ);
    const float h = hsm[mm], w = wsm[mm];
    ax = fmaf(tanh_fast(c4.x + h), w, ax);
    ay = fmaf(tanh_fast(c4.y + h), w, ay);
    az = fmaf(tanh_fast(c4.z + h), w, az);
    aw = fmaf(tanh_fast(c4.w + h), w, aw);
  }
  *(float4*)(psc + ((size_t)b * MSPLIT + mh) * NSQ + n0) = make_float4(ax, ay, az, aw);
}

// ---------------- argmax + LSE + lp + mask update + x-plane feedback
__global__ __launch_bounds__(256) void k_argmax(
    const float* __restrict__ psc, float* __restrict__ mask,
    const float* __restrict__ gum, const float* __restrict__ b2p,
    float* __restrict__ lp, const float* __restrict__ ctx,
    unsigned short* __restrict__ xhh, unsigned short* __restrict__ xhl,
    float* __restrict__ outv, int step) {
  const int b = blockIdx.x, tid = threadIdx.x;
  __shared__ float rv[256], rs[256], rm[256];
  __shared__ int ri[256];
  __shared__ int sel;
  const float b2 = b2p[0];
  const int n0 = tid * 4;
  const float4 m4 = *(const float4*)(mask + (size_t)b * NSQ + n0);
  float sc[4] = {b2 + m4.x, b2 + m4.y, b2 + m4.z, b2 + m4.w};
#pragma unroll
  for (int mh = 0; mh < MSPLIT; ++mh) {
    const float4 p4 = *(const float4*)(psc + ((size_t)b * MSPLIT + mh) * NSQ + n0);
    sc[0] += p4.x; sc[1] += p4.y; sc[2] += p4.z; sc[3] += p4.w;
  }
  const float4 g4 = *(const float4*)(gum + ((size_t)step * BSZ + b) * NSQ + n0);
  const float gv[4] = {g4.x, g4.y, g4.z, g4.w};
  float bestv = -1e30f, bests = 0.0f, msc = -1e30f;
  int bestn = 0;
#pragma unroll
  for (int q = 0; q < 4; ++q) {
    const float v = sc[q] + gv[q];
    if (v > bestv) { bestv = v; bestn = n0 + q; bests = sc[q]; }
    msc = fmaxf(msc, sc[q]);
  }
  rv[tid] = bestv; ri[tid] = bestn; rs[tid] = bests; rm[tid] = msc;
  __syncthreads();
  for (int o = 128; o > 0; o >>= 1) {
    if (tid < o) {
      if (rv[tid + o] > rv[tid] || (rv[tid + o] == rv[tid] && ri[tid + o] < ri[tid])) {
        rv[tid] = rv[tid + o]; ri[tid] = ri[tid + o]; rs[tid] = rs[tid + o];
      }
      rm[tid] = fmaxf(rm[tid], rm[tid + o]);
    }
    __syncthreads();
  }
  const float M = rm[0];
  __syncthreads();
  float se = 0.0f;
#pragma unroll
  for (int q = 0; q < 4; ++q)
    se += __builtin_amdgcn_exp2f((sc[q] - M) * 1.4426950408889634f);
  rm[tid] = se;
  __syncthreads();
  for (int o = 128; o > 0; o >>= 1) {
    if (tid < o) rm[tid] += rm[tid + o];
    __syncthreads();
  }
  if (tid == 0) {
    const int n = ri[0];
    const float lse = M + logf(rm[0]);
    const float nlp = lp[b] + rs[0] - lse;
    lp[b] = nlp;
    mask[(size_t)b * NSQ + n] = NEGV;
    outv[step * BSZ + b] = (float)n;
    if (step == NSTEPC - 1) outv[NSTEPC * BSZ + b] = nlp;
    sel = n;
  }
  __syncthreads();
  const int n = sel;
  if (tid < 96) {  // x feedback: split ctx row into xh planes (96 chunks)
    const float* src = ctx + ((size_t)b * NSQ + n) * IND + tid * 8;
    const int tile = tid >> 2, c4 = tid & 3;
    const int slot = c4 ^ ((b >> 1) & 3);
    const size_t ub = (((size_t)tile * 128 + b) * 4 + slot) * 8;
    short8v hi, lo;
    split2(*(const float4*)src, *(const float4*)(src + 4), hi, lo);
    *(short8v*)&xhh[ub] = hi;
    *(short8v*)&xhl[ub] = lo;
  }
}

extern "C" void kernel_launch(void* const* d_in, const int* in_sizes, int n_in,
                              void* d_out, int out_size, void* d_ws, size_t ws_size,
                              hipStream_t stream) {
  const float* target_emb = (const float*)d_in[0];
  const float* ctx_emb   = (const float*)d_in[1];
  const int*   ctx_len   = (const int*)d_in[3];
  const float* W_ih = (const float*)d_in[5];
  const float* W_hh = (const float*)d_in[6];
  const float* b_ih = (const float*)d_in[7];
  const float* b_hh = (const float*)d_in[8];
  const float* W1c  = (const float*)d_in[9];
  const float* W1h  = (const float*)d_in[10];
  const float* b1   = (const float*)d_in[11];
  const float* w2   = (const float*)d_in[12];
  const float* b2   = (const float*)d_in[13];
  const float* gumbel = (const float*)d_in[14];
  float* out = (float*)d_out;

  float* ws = (float*)d_ws;
  size_t off = 0;
  auto alloc = [&](size_t n) { float* p = ws + off; off += (n + 63) & ~(size_t)63; return p; };

  float* cp   = alloc((size_t)BSZ * MLPD * NSQ);        // 268 MB
  float* gp   = alloc((size_t)KSGATE * BSZ * G4D);
  float* hpp  = alloc((size_t)BSZ * MLPD);
  float* psc  = alloc((size_t)BSZ * MSPLIT * NSQ);
  float* mask = alloc((size_t)BSZ * NSQ);
  float* cst  = alloc((size_t)BSZ * HIDD);
  float* lp   = alloc(128);
  unsigned short* wch = (unsigned short*)alloc(196608);   // 512x768 u16
  unsigned short* wcl = (unsigned short*)alloc(196608);
  unsigned short* wgh = (unsigned short*)alloc(1310720);  // 2048x1280 u16
  unsigned short* wgl = (unsigned short*)alloc(1310720);
  unsigned short* xhh = (unsigned short*)alloc(81920);    // 128x1280 u16
  unsigned short* xhl = (unsigned short*)alloc(81920);
  // ctx planes last (403 MB) so the fallback path doesn't need them
  const size_t ctx_plane_elems = (size_t)BSZ * NSQ * IND / 2;  // u16 count per plane, as floats/2
  const bool presplit = ws_size >= (off + 2 * ((ctx_plane_elems + 63) & ~(size_t)63)) * 4;
  unsigned short* cxh = nullptr; unsigned short* cxl = nullptr;
  if (presplit) {
    cxh = (unsigned short*)alloc(ctx_plane_elems);   // 128*1024*768 u16 = 192 MB
    cxl = (unsigned short*)alloc(ctx_plane_elems);
  }

  k_prep_w<<<1472, 256, 0, stream>>>(W1c, W_ih, W_hh, wch, wcl, wgh, wgl);
  k_init2<<<BSZ, 256, 0, stream>>>(target_emb, ctx_len, mask, cst, lp, xhh, xhl);

  if (presplit) {
    k_prep_ctx<<<1024, 256, 0, stream>>>(ctx_emb, ctx_len, cxh, cxl);
    k_ctx4<<<dim3(MLPD / 128, 1024), 256, 0, stream>>>(
        cxh, cxl, wch, wcl, b1, ctx_len, cp);
  } else {
    k_ctx2<<<dim3(2, 2048), 256, 0, stream>>>(ctx_emb, wch, wcl, b1, ctx_len, cp);
  }

  for (int t = 0; t < NSTEPC; ++t) {
    k_gates<<<dim3(16, KSGATE), 256, 0, stream>>>(xhh, xhl, wgh, wgl, gp);
    k_lstm2<<<BSZ, 512, 0, stream>>>(gp, b_ih, b_hh, W1h, cst, xhh, xhl, hpp);
    k_scores<<<dim3(MSPLIT, BSZ), 256, 0, stream>>>(cp, hpp, w2, ctx_len, psc);
    k_argmax<<<BSZ, 256, 0, stream>>>(psc, mask, gumbel, b2, lp, ctx_emb, xhh, xhl, out, t);
  }
}

// Round 6
// 857.727 us; speedup vs baseline: 1.8948x; 1.2315x over previous
//
#include <hip/hip_runtime.h>
#include <hip/hip_bf16.h>

#define BSZ 128
#define NSQ 1024
#define NSTEPC 8
#define IND 768
#define HIDD 512
#define G4D 2048
#define MLPD 512
#define KXD 1280
#define NEGV -100000.0f
#define KSG 16   // K-split chunks for gates gemm (1280/16 = 80 = 5 tiles)
#define KSH 8    // K-split chunks for hproj gemm (512/8 = 64 = 4 tiles)
#define MSPLIT 4 // m-split for scores kernel

typedef __attribute__((ext_vector_type(4))) float f32x4;
typedef __attribute__((ext_vector_type(8))) short short8v;

__device__ __forceinline__ void gl16(const unsigned short* g, unsigned short* l) {
  __builtin_amdgcn_global_load_lds(
      (const __attribute__((address_space(1))) unsigned int*)(g),
      (__attribute__((address_space(3))) unsigned int*)(l), 16, 0, 0);
}

__device__ __forceinline__ void split2(float4 f0, float4 f1, short8v& hi, short8v& lo) {
  float fv[8] = {f0.x, f0.y, f0.z, f0.w, f1.x, f1.y, f1.z, f1.w};
#pragma unroll
  for (int j = 0; j < 8; ++j) {
    const unsigned ub = __builtin_bit_cast(unsigned, fv[j]);
    const unsigned hb = ub & 0xFFFF0000u;
    const float lf = fv[j] - __builtin_bit_cast(float, hb);
    hi[j] = (short)(hb >> 16);
    lo[j] = (short)(__builtin_bit_cast(unsigned, lf) >> 16);
  }
}

// tanh(x) = 1 - 2/(e^{2x}+1)
__device__ __forceinline__ float tanh_fast(float x) {
  x = fminf(fmaxf(x, -15.0f), 15.0f);
  float e = __builtin_amdgcn_exp2f(x * 2.8853900817779268f);
  float r = __builtin_amdgcn_rcpf(e + 1.0f);
  return fmaf(-2.0f, r, 1.0f);
}

// ---------------- one-time: split W1c into bf16 hi/lo planes, gl16-ready tiled layout
// unit16B = ((rb*24 + tile)*128 + row128)*4 + slot, slot = c4 ^ ((row>>1)&3)
__global__ __launch_bounds__(256) void k_prep_w1c(
    const float* __restrict__ W1c,
    unsigned short* __restrict__ wch, unsigned short* __restrict__ wcl) {
  const int c = blockIdx.x * 256 + threadIdx.x;
  if (c >= 49152) return;  // 512 rows x 96 chunks
  const int row = c / 96, wc = c - row * 96;
  const int tile = wc >> 2, c4 = wc & 3;
  const int slot = c4 ^ ((row >> 1) & 3);
  const size_t unit = ((size_t)((row >> 7) * 24 + tile) * 128 + (row & 127)) * 4 + slot;
  const float* src = W1c + (size_t)row * IND + wc * 8;
  const float4 f0 = *(const float4*)src, f1 = *(const float4*)(src + 4);
  short8v hi, lo;
  split2(f0, f1, hi, lo);
  *(short8v*)(wch + unit * 8) = hi;
  *(short8v*)(wcl + unit * 8) = lo;
}

// ---------------- init: mask from ctx_len, xh = [target_emb | 0], c=0, lp=0
__global__ __launch_bounds__(256) void k_init(
    const float* __restrict__ te, const int* __restrict__ cl,
    float* __restrict__ mask, float* __restrict__ xh,
    float* __restrict__ cst, float* __restrict__ lp) {
  const int b = blockIdx.x, tid = threadIdx.x;
  const int L = cl[b];
  for (int n = tid; n < NSQ; n += 256) mask[(size_t)b*NSQ + n] = (n >= L) ? NEGV : 0.0f;
  for (int d = tid; d < IND; d += 256) xh[(size_t)b*KXD + d] = te[(size_t)b*IND + d];
  for (int j = tid; j < HIDD; j += 256) {
    xh[(size_t)b*KXD + IND + j] = 0.0f;
    cst[(size_t)b*HIDD + j] = 0.0f;
  }
  if (tid == 0) lp[b] = 0.0f;
}

// ---------------- ctx_part GEMM, 2-phase double-buffered, XCD-swizzled:
// cp[b][m][n] = sum_k ctx[b,n,k]*W1c[m,k] + b1[m]; split-bf16 (hh+hl+lh)
// 256 thr / 4 waves (2m x 2n); tile m=128, n=128, BK=32, 24 K-steps.
// W via global_load_lds from pre-split planes; ctx reg-split in-kernel.
__global__ __launch_bounds__(256) void k_ctx5(
    const float* __restrict__ ctx,
    const unsigned short* __restrict__ wch, const unsigned short* __restrict__ wcl,
    const float* __restrict__ bias, const int* __restrict__ clen,
    float* __restrict__ cp) {
  __shared__ __align__(16) unsigned short sWh[2][4096], sWl[2][4096];
  __shared__ __align__(16) unsigned short sCh[2][4096], sCl[2][4096];
  // bijective XCD swizzle: 4096 blocks, 8 XCDs -> all 4 m-blocks of a row-block
  // land on one XCD (shared L2 for the ctx panel)
  const int bid = blockIdx.x;
  const int v = ((bid & 7) << 9) + (bid >> 3);
  const int mx = v & 3;          // m-block (4)
  const int rbC = v >> 2;        // ctx row-block (1024)
  const int b = rbC >> 3;
  const int nbase = (rbC & 7) << 7;
  if (nbase >= clen[b]) return;  // masked region: cp never read there
  const int i0 = rbC << 7;
  const int m0 = mx << 7;
  const int tid = threadIdx.x;
  const int lane = tid & 63, wid = tid >> 6;
  const int wm = wid & 1, wn = wid >> 1;
  const int l15 = lane & 15, l4 = lane >> 4;
  // ctx conversion: 2 chunks/thread (512 chunks = 128 rows x 4 k-slots)
  const int c0r = tid >> 2, cs = tid & 3;
  const int c1r = 64 + c0r;
  const int k0rd = cs ^ ((c0r >> 1) & 3);
  const int k1rd = cs ^ ((c1r >> 1) & 3);
  const float* csrc0 = ctx + (size_t)(i0 + c0r) * IND + k0rd * 8;
  const float* csrc1 = ctx + (size_t)(i0 + c1r) * IND + k1rd * 8;

  // ---- prologue: stage tile 0
#pragma unroll
  for (int i = 0; i < 4; ++i) {
    const int seg = wid * 4 + i;  // 16 segs: 0-7 Wh, 8-15 Wl
    const unsigned short* g = ((seg & 8) ? wcl : wch) +
        (size_t)(mx * 24) * 4096 + (seg & 7) * 512 + lane * 8;
    unsigned short* l = ((seg & 8) ? sWl[0] : sWh[0]) + (seg & 7) * 512;
    gl16(g, l);
  }
  {
    short8v hi, lo;
    split2(*(const float4*)csrc0, *(const float4*)(csrc0 + 4), hi, lo);
    *(short8v*)&sCh[0][tid * 8] = hi;
    *(short8v*)&sCl[0][tid * 8] = lo;
    split2(*(const float4*)csrc1, *(const float4*)(csrc1 + 4), hi, lo);
    *(short8v*)&sCh[0][(256 + tid) * 8] = hi;
    *(short8v*)&sCl[0][(256 + tid) * 8] = lo;
  }
  __syncthreads();

  f32x4 acc[4][4] = {};  // [fm][fn]
  for (int t = 0; t < 24; ++t) {
    const int cur = t & 1, nb = cur ^ 1;
    float4 r00, r01, r10, r11;
    if (t + 1 < 24) {  // issue next-tile staging FIRST (T3-min)
#pragma unroll
      for (int i = 0; i < 4; ++i) {
        const int seg = wid * 4 + i;
        const unsigned short* g = ((seg & 8) ? wcl : wch) +
            (size_t)(mx * 24 + t + 1) * 4096 + (seg & 7) * 512 + lane * 8;
        unsigned short* l = ((seg & 8) ? sWl[nb] : sWh[nb]) + (seg & 7) * 512;
        gl16(g, l);
      }
      r00 = *(const float4*)(csrc0 + (t + 1) * 32);
      r01 = *(const float4*)(csrc0 + (t + 1) * 32 + 4);
      r10 = *(const float4*)(csrc1 + (t + 1) * 32);
      r11 = *(const float4*)(csrc1 + (t + 1) * 32 + 4);
    }
    // ---- compute current tile
    short8v ah[4], al[4], bh[4], bl[4];
#pragma unroll
    for (int f = 0; f < 4; ++f) {
      const int rw = wm * 64 + f * 16 + l15;
      const int so = (l4 ^ ((rw >> 1) & 3)) << 3;
      ah[f] = *(const short8v*)&sWh[cur][rw * 32 + so];
      al[f] = *(const short8v*)&sWl[cur][rw * 32 + so];
      const int rc = wn * 64 + f * 16 + l15;
      const int sc = (l4 ^ ((rc >> 1) & 3)) << 3;
      bh[f] = *(const short8v*)&sCh[cur][rc * 32 + sc];
      bl[f] = *(const short8v*)&sCl[cur][rc * 32 + sc];
    }
#pragma unroll
    for (int fm = 0; fm < 4; ++fm)
#pragma unroll
      for (int fn = 0; fn < 4; ++fn) {
        acc[fm][fn] = __builtin_amdgcn_mfma_f32_16x16x32_bf16(ah[fm], bh[fn], acc[fm][fn], 0, 0, 0);
        acc[fm][fn] = __builtin_amdgcn_mfma_f32_16x16x32_bf16(ah[fm], bl[fn], acc[fm][fn], 0, 0, 0);
        acc[fm][fn] = __builtin_amdgcn_mfma_f32_16x16x32_bf16(al[fm], bh[fn], acc[fm][fn], 0, 0, 0);
      }
    if (t + 1 < 24) {  // convert+write next ctx tile (into nb, safe pre-barrier)
      short8v hi, lo;
      split2(r00, r01, hi, lo);
      *(short8v*)&sCh[nb][tid * 8] = hi;
      *(short8v*)&sCl[nb][tid * 8] = lo;
      split2(r10, r11, hi, lo);
      *(short8v*)&sCh[nb][(256 + tid) * 8] = hi;
      *(short8v*)&sCl[nb][(256 + tid) * 8] = lo;
    }
    __syncthreads();
  }
  // epilogue: D row m = (l>>4)*4 + reg, col n = l&15 (16-lane 64B segments)
#pragma unroll
  for (int fm = 0; fm < 4; ++fm) {
#pragma unroll
    for (int r = 0; r < 4; ++r) {
      const int m = m0 + wm * 64 + fm * 16 + l4 * 4 + r;
      const float bb = bias[m];
      float* dst = cp + (((size_t)(b * MLPD + m)) << 10) + nbase + wn * 64 + l15;
#pragma unroll
      for (int fn = 0; fn < 4; ++fn)
        dst[fn * 16] = acc[fm][fn][r] + bb;
    }
  }
}

// ---------------- K-split partial GEMM: P[kc][i][n] = sum_{k in chunk} A[i,acol+k]*B(n,k)
__global__ __launch_bounds__(256) void k_pgemm(
    const float* __restrict__ A, int lda, int acol,
    const float* __restrict__ B0, int ldb0, int kb,
    const float* __restrict__ B1, int ldb1,
    int kTiles, int N, float* __restrict__ P) {
  __shared__ float As[16][128];
  __shared__ float Bs[16][132];
  const int n0 = blockIdx.x * 128;
  const int kc0 = blockIdx.y * kTiles * 16;
  const int tid = threadIdx.x;
  const int tn = tid & 15;   // n-group
  const int ta = tid >> 4;   // i-group
  float acc[8][8] = {};      // [ri][ni]
  for (int t = 0; t < kTiles; ++t) {
    const int k0 = kc0 + t * 16;
#pragma unroll
    for (int u = 0; u < 2; ++u) {
      const int v = tid + u * 256;
      const int r = v >> 2, kc = v & 3;
      const float4 a4 = *(const float4*)(A + (size_t)r * lda + acol + k0 + kc * 4);
      As[kc*4+0][r] = a4.x; As[kc*4+1][r] = a4.y; As[kc*4+2][r] = a4.z; As[kc*4+3][r] = a4.w;
      const float* bp = (k0 < kb) ? (B0 + (size_t)(n0 + r) * ldb0 + k0 + kc * 4)
                                  : (B1 + (size_t)(n0 + r) * ldb1 + (k0 - kb) + kc * 4);
      const float4 b4 = *(const float4*)bp;
      Bs[kc*4+0][r] = b4.x; Bs[kc*4+1][r] = b4.y; Bs[kc*4+2][r] = b4.z; Bs[kc*4+3][r] = b4.w;
    }
    __syncthreads();
#pragma unroll
    for (int kk = 0; kk < 16; ++kk) {
      float av[8], bv[8];
#pragma unroll
      for (int q = 0; q < 8; ++q) av[q] = As[kk][ta*8+q];
#pragma unroll
      for (int q = 0; q < 8; ++q) bv[q] = Bs[kk][tn*8+q];
#pragma unroll
      for (int ri = 0; ri < 8; ++ri)
#pragma unroll
        for (int ni = 0; ni < 8; ++ni)
          acc[ri][ni] = fmaf(av[ri], bv[ni], acc[ri][ni]);
    }
    __syncthreads();
  }
#pragma unroll
  for (int ri = 0; ri < 8; ++ri) {
    const int i = ta * 8 + ri;
    float* p = P + ((size_t)blockIdx.y * BSZ + i) * N + n0 + tn * 8;
    *(float4*)(p + 0) = make_float4(acc[ri][0], acc[ri][1], acc[ri][2], acc[ri][3]);
    *(float4*)(p + 4) = make_float4(acc[ri][4], acc[ri][5], acc[ri][6], acc[ri][7]);
  }
}

// ---------------- reduce gate partials + LSTM cell update (writes c, xh h-part)
__global__ __launch_bounds__(512) void k_lstm(
    const float* __restrict__ gp, const float* __restrict__ b_ih,
    const float* __restrict__ b_hh, float* __restrict__ cst, float* __restrict__ xh) {
  const int b = blockIdx.x, j = threadIdx.x;
  float g[4];
#pragma unroll
  for (int q = 0; q < 4; ++q) {
    float s = b_ih[q*HIDD + j] + b_hh[q*HIDD + j];
#pragma unroll
    for (int ks = 0; ks < KSG; ++ks) s += gp[((size_t)ks*BSZ + b)*G4D + q*HIDD + j];
    g[q] = s;
  }
  const float c_old = cst[(size_t)b*HIDD + j];
  const float ig = 1.0f / (1.0f + expf(-g[0]));
  const float fg = 1.0f / (1.0f + expf(-g[1]));
  const float gg = tanhf(g[2]);
  const float og = 1.0f / (1.0f + expf(-g[3]));
  const float cn = fg * c_old + ig * gg;
  const float hn = og * tanhf(cn);
  cst[(size_t)b*HIDD + j] = cn;
  xh[(size_t)b*KXD + IND + j] = hn;
}

// ---------------- scores partial: psc[b][mh][n] = sum_{m in mh-range} tanh(cp+hp)*w2
__global__ __launch_bounds__(256) void k_scores(
    const float* __restrict__ cp, const float* __restrict__ hpp,
    const float* __restrict__ w2, const int* __restrict__ clen,
    float* __restrict__ psc) {
  const int mh = blockIdx.x;  // [0,MSPLIT)
  const int b = blockIdx.y;
  const int tid = threadIdx.x;
  __shared__ float hs[128], ws[128];
  if (tid < 128) {
    const int m = mh * 128 + tid;
    float s = 0.0f;
#pragma unroll
    for (int ks = 0; ks < KSH; ++ks) s += hpp[((size_t)ks*BSZ + b)*MLPD + m];
    hs[tid] = s;
    ws[tid] = w2[m];
  }
  __syncthreads();
  const int len = clen[b];
  const int n0 = tid * 4;
  if (n0 >= len) return;
  float ax = 0, ay = 0, az = 0, aw = 0;
  const float* base = cp + ((size_t)b * MLPD + mh * 128) * NSQ + n0;
#pragma unroll 4
  for (int mm = 0; mm < 128; ++mm) {
    const float4 c4 = *(const float4*)(base + (size_t)mm * NSQ);
    const float h = hs[mm], w = ws[mm];
    ax = fmaf(tanh_fast(c4.x + h), w, ax);
    ay = fmaf(tanh_fast(c4.y + h), w, ay);
    az = fmaf(tanh_fast(c4.z + h), w, az);
    aw = fmaf(tanh_fast(c4.w + h), w, aw);
  }
  *(float4*)(psc + ((size_t)b * MSPLIT + mh) * NSQ + n0) = make_float4(ax, ay, az, aw);
}

// ---------------- argmax + LSE + lp + mask/x update (one block per batch row)
__global__ __launch_bounds__(256) void k_argmax(
    const float* __restrict__ psc, float* __restrict__ mask,
    const float* __restrict__ gum, const float* __restrict__ b2p,
    float* __restrict__ lp, const float* __restrict__ ctx,
    float* __restrict__ xh, float* __restrict__ outv, int step) {
  const int b = blockIdx.x, tid = threadIdx.x;
  __shared__ float rv[256], rs[256], rm[256];
  __shared__ int ri[256];
  __shared__ int sel;
  const float b2 = b2p[0];
  const int n0 = tid * 4;
  const float4 m4 = *(const float4*)(mask + (size_t)b * NSQ + n0);
  float sc[4] = {b2 + m4.x, b2 + m4.y, b2 + m4.z, b2 + m4.w};
#pragma unroll
  for (int mh = 0; mh < MSPLIT; ++mh) {
    const float4 p4 = *(const float4*)(psc + ((size_t)b * MSPLIT + mh) * NSQ + n0);
    sc[0] += p4.x; sc[1] += p4.y; sc[2] += p4.z; sc[3] += p4.w;
  }
  const float4 g4 = *(const float4*)(gum + ((size_t)step * BSZ + b) * NSQ + n0);
  const float gv[4] = {g4.x, g4.y, g4.z, g4.w};
  float bestv = -1e30f, bests = 0.0f, msc = -1e30f;
  int bestn = 0;
#pragma unroll
  for (int q = 0; q < 4; ++q) {
    const float v = sc[q] + gv[q];
    if (v > bestv) { bestv = v; bestn = n0 + q; bests = sc[q]; }
    msc = fmaxf(msc, sc[q]);
  }
  rv[tid] = bestv; ri[tid] = bestn; rs[tid] = bests; rm[tid] = msc;
  __syncthreads();
  for (int o = 128; o > 0; o >>= 1) {
    if (tid < o) {
      if (rv[tid+o] > rv[tid] || (rv[tid+o] == rv[tid] && ri[tid+o] < ri[tid])) {
        rv[tid] = rv[tid+o]; ri[tid] = ri[tid+o]; rs[tid] = rs[tid+o];
      }
      rm[tid] = fmaxf(rm[tid], rm[tid+o]);
    }
    __syncthreads();
  }
  const float M = rm[0];
  __syncthreads();
  float se = 0.0f;
#pragma unroll
  for (int q = 0; q < 4; ++q)
    se += __builtin_amdgcn_exp2f((sc[q] - M) * 1.4426950408889634f);
  rm[tid] = se;
  __syncthreads();
  for (int o = 128; o > 0; o >>= 1) {
    if (tid < o) rm[tid] += rm[tid+o];
    __syncthreads();
  }
  if (tid == 0) {
    const int n = ri[0];
    const float lse = M + logf(rm[0]);
    const float nlp = lp[b] + rs[0] - lse;
    lp[b] = nlp;
    mask[(size_t)b * NSQ + n] = NEGV;
    outv[step * BSZ + b] = (float)n;
    if (step == NSTEPC - 1) outv[NSTEPC * BSZ + b] = nlp;
    sel = n;
  }
  __syncthreads();
  const int n = sel;
  const float4* src = (const float4*)(ctx + ((size_t)b * NSQ + n) * IND);
  float4* dst = (float4*)(xh + (size_t)b * KXD);
  for (int d = tid; d < IND / 4; d += 256) dst[d] = src[d];
}

extern "C" void kernel_launch(void* const* d_in, const int* in_sizes, int n_in,
                              void* d_out, int out_size, void* d_ws, size_t ws_size,
                              hipStream_t stream) {
  const float* target_emb = (const float*)d_in[0];
  const float* ctx_emb   = (const float*)d_in[1];
  const int*   ctx_len   = (const int*)d_in[3];
  const float* W_ih = (const float*)d_in[5];
  const float* W_hh = (const float*)d_in[6];
  const float* b_ih = (const float*)d_in[7];
  const float* b_hh = (const float*)d_in[8];
  const float* W1c  = (const float*)d_in[9];
  const float* W1h  = (const float*)d_in[10];
  const float* b1   = (const float*)d_in[11];
  const float* w2   = (const float*)d_in[12];
  const float* b2   = (const float*)d_in[13];
  const float* gumbel = (const float*)d_in[14];
  float* out = (float*)d_out;

  float* ws = (float*)d_ws;
  size_t off = 0;
  auto alloc = [&](size_t n) { float* p = ws + off; off += (n + 63) & ~(size_t)63; return p; };

  float* cp   = alloc((size_t)BSZ * MLPD * NSQ);   // 268 MB
  float* gp   = alloc((size_t)KSG * BSZ * G4D);
  float* hpp  = alloc((size_t)KSH * BSZ * MLPD);
  float* psc  = alloc((size_t)BSZ * MSPLIT * NSQ);
  float* mask = alloc((size_t)BSZ * NSQ);
  float* xh   = alloc((size_t)BSZ * KXD);
  float* cst  = alloc((size_t)BSZ * HIDD);
  float* lp   = alloc(128);
  unsigned short* wch = (unsigned short*)alloc(196608);   // 512x768 u16
  unsigned short* wcl = (unsigned short*)alloc(196608);

  k_prep_w1c<<<192, 256, 0, stream>>>(W1c, wch, wcl);
  k_init<<<BSZ, 256, 0, stream>>>(target_emb, ctx_len, mask, xh, cst, lp);
  k_ctx5<<<4096, 256, 0, stream>>>(ctx_emb, wch, wcl, b1, ctx_len, cp);

  for (int t = 0; t < NSTEPC; ++t) {
    // gates partials: N=2048, K=1280 split in 16 chunks of 5 tiles
    k_pgemm<<<dim3(G4D/128, KSG), 256, 0, stream>>>(
        xh, KXD, 0, W_ih, IND, IND, W_hh, HIDD, 5, G4D, gp);
    k_lstm<<<BSZ, 512, 0, stream>>>(gp, b_ih, b_hh, cst, xh);
    // hproj partials: N=512, K=512 split in 8 chunks of 4 tiles
    k_pgemm<<<dim3(MLPD/128, KSH), 256, 0, stream>>>(
        xh, KXD, IND, W1h, HIDD, 1 << 30, nullptr, 0, 4, MLPD, hpp);
    k_scores<<<dim3(MSPLIT, BSZ), 256, 0, stream>>>(cp, hpp, w2, ctx_len, psc);
    k_argmax<<<BSZ, 256, 0, stream>>>(psc, mask, gumbel, b2, lp, ctx_emb, xh, out, t);
  }
}